// Round 2
// baseline (10219.150 us; speedup 1.0000x reference)
//
#include <hip/hip_runtime.h>
#include <stdint.h>

typedef __bf16 bf16;
typedef __bf16 bf16x8 __attribute__((ext_vector_type(8)));
typedef short  s16x8  __attribute__((ext_vector_type(8)));
typedef float  f32x4  __attribute__((ext_vector_type(4)));
typedef uint32_t u32;

#define NB   1024
#define LSEQ 336
#define HID  384
#define HOR  18
#define SMEM_BYTES 36864

// ---------------- device-global scratch (avoids ws_size limits) ----------------
__device__ bf16  g_A0[2*NB*416];      // [2][1024][416]: h0 | x_t | pad
__device__ bf16  g_A1[2*NB*768];      // [2][1024][768]: h0_out | h1
__device__ bf16  g_Adec[2*NB*768];    // [2][1024][768]: din | h_dec
__device__ bf16  g_Adin[NB*416];      // [1024][416]: y | feat4 | ctx384 | pad
__device__ float g_c0[NB*HID];
__device__ float g_c1[NB*HID];
__device__ float g_cdec[NB*HID];
__device__ float g_u[NB*HID];
__device__ float g_bias0[1536], g_bias1[1536], g_biasd[1536], g_biasdin[384];
__device__ bf16  g_Bp0[12*13*4096];
__device__ bf16  g_Bp1[12*24*4096];
__device__ bf16  g_Bpd[12*24*4096];
__device__ bf16  g_Bpi[3*13*4096];
__device__ bf16  g_Bpu[3*12*4096];
__device__ bf16  g_enc[(size_t)NB*LSEQ*HID];   // 264 MB, [B][L][H]

__device__ __forceinline__ float sigf(float x){ return 1.0f/(1.0f + __expf(-x)); }
__device__ __forceinline__ float tanh_f(float x){
  x = fminf(fmaxf(x, -15.f), 15.f);
  float e = __expf(2.f*x);
  return (e - 1.f)/(e + 1.f);
}

// ---------------- per-call state zeroing (replay determinism) ----------------
__global__ void zero_state_k(){
  int i = blockIdx.x*blockDim.x + threadIdx.x;
  int st = gridDim.x*blockDim.x;
  bf16 z = (bf16)0.f;
  for(int k=i;k<2*NB*416;k+=st) g_A0[k]=z;
  for(int k=i;k<2*NB*768;k+=st) g_A1[k]=z;
  for(int k=i;k<NB*HID;k+=st){ g_c0[k]=0.f; g_c1[k]=0.f; g_cdec[k]=0.f; }
}

// ---------------- weight packs ----------------
// gates pack: out[jb][ks][tt(8)][lane(64)][8], n = (tt>>1)*384 + jb*32 + (tt&1)*16 + (lane&15)
// mode 0 (enc L0): k<384 -> W1=Whh0[n][k]; 384<=k<392 -> W2=Wih0[n][k-384]; else 0   (K=416)
// mode 1 (enc L1): k<384 -> W1=Wih1[n][k]; else W2=Whh1[n][k-384]                     (K=768)
// mode 2 (dec):    k<384 -> W1=dWih[n][k]; else W2=dWhh[n][k-384]                     (K=768)
__global__ void pack_gates_k(int mode, const float* __restrict__ W1, const float* __restrict__ W2,
                             int nks){
  bf16* out = (mode==0)? g_Bp0 : (mode==1)? g_Bp1 : g_Bpd;
  size_t idx = (size_t)blockIdx.x*256 + threadIdx.x;
  size_t total = (size_t)12*nks*512;
  if(idx >= total) return;
  int lane = (int)(idx & 63);
  int tt   = (int)((idx>>6) & 7);
  size_t tmp = idx >> 9;
  int ks = (int)(tmp % nks);
  int jb = (int)(tmp / nks);
  int n  = (tt>>1)*HID + jb*32 + (tt&1)*16 + (lane&15);
  int kb = ks*32 + (lane>>4)*8;
  bf16x8 v;
  #pragma unroll
  for(int i=0;i<8;i++){
    int k = kb + i;
    float f;
    if(mode==0) f = (k<384) ? W1[(size_t)n*384 + k] : (k<392 ? W2[(size_t)n*8 + (k-384)] : 0.f);
    else        f = (k<384) ? W1[(size_t)n*384 + k] : W2[(size_t)n*384 + (k-384)];
    v[i] = (bf16)f;
  }
  *(bf16x8*)(out + idx*8) = v;
}

// plain pack: out[nb][ks][tt(8)][lane][8], n = nb*128 + tt*16 + (lane&15)
// mode 0 (dec_in): W [384][389], B[k][n] = W[n][k] (k<389 else 0)  (K=416) -> g_Bpi
// mode 1 (Wa):     W [384][384], B[k][n] = W[k][n]                 (K=384) -> g_Bpu
__global__ void pack_plain_k(int mode, const float* __restrict__ W, int nks, int nb_cnt){
  bf16* out = mode ? g_Bpu : g_Bpi;
  size_t idx = (size_t)blockIdx.x*256 + threadIdx.x;
  size_t total = (size_t)nb_cnt*nks*512;
  if(idx>=total) return;
  int lane = (int)(idx&63);
  int tt   = (int)((idx>>6)&7);
  size_t tmp = idx>>9;
  int ks = (int)(tmp%nks);
  int nb = (int)(tmp/nks);
  int n  = nb*128 + tt*16 + (lane&15);
  int kb = ks*32 + (lane>>4)*8;
  bf16x8 v;
  #pragma unroll
  for(int i=0;i<8;i++){
    int k = kb+i;
    float f;
    if(mode==0) f = (k<389)? W[(size_t)n*389 + k] : 0.f;
    else        f = W[(size_t)k*384 + n];
    v[i]=(bf16)f;
  }
  *(bf16x8*)(out + idx*8) = v;
}

__global__ void prep_misc_k(const float* bih0,const float* bhh0,const float* bih1,const float* bhh1,
                            const float* dbih,const float* dbhh,const float* dinb,
                            const float* x){
  int i = blockIdx.x*256 + threadIdx.x;
  if(i<1536){ g_bias0[i]=bih0[i]+bhh0[i]; g_bias1[i]=bih1[i]+bhh1[i]; g_biasd[i]=dbih[i]+dbhh[i]; }
  if(i<384) g_biasdin[i]=dinb[i];
  if(i<NB*8){ int b=i>>3, k=i&7; g_A0[(size_t)b*416 + 384 + k] = (bf16)x[(size_t)b*LSEQ*8 + k]; }
}

// ---------------- GEMM core ----------------
// Block: 256 thr (4 waves, 2x2). Tile: 128m x 128n (8 n-tiles of 16). K staged in 32-chunks.
// LDS: A[2][128][40pad] bf16 (10240B each), B[2][8 tiles][64][8] bf16 (8192B each).
struct SReg { s16x8 a0,a1,b0,b1; };

__device__ __forceinline__ void stage_load(const bf16* __restrict__ A, int ldA,
                                           const bf16* __restrict__ Bk, int tid, SReg& sr){
  int c0 = tid, c1 = tid+256;
  sr.a0 = *(const s16x8*)(A + (size_t)(c0>>2)*ldA + (c0&3)*8);
  sr.a1 = *(const s16x8*)(A + (size_t)(c1>>2)*ldA + (c1&3)*8);
  const s16x8* B8 = (const s16x8*)Bk;
  sr.b0 = B8[c0]; sr.b1 = B8[c1];
}

__device__ __forceinline__ void stage_write(char* Ab, char* Bb, int tid, const SReg& sr){
  int c0 = tid, c1 = tid+256;
  *(s16x8*)(Ab + (c0>>2)*80 + (c0&3)*16) = sr.a0;
  *(s16x8*)(Ab + (c1>>2)*80 + (c1&3)*16) = sr.a1;
  *(s16x8*)(Bb + c0*16) = sr.b0;
  *(s16x8*)(Bb + c1*16) = sr.b1;
}

__device__ __forceinline__ void gemm_core(const bf16* __restrict__ A, int ldA,
                                          const bf16* __restrict__ Bp, int nks,
                                          char* smem, f32x4 acc[4][4]){
  const int tid = threadIdx.x;
  const int lane = tid & 63, wv = tid>>6, wm = wv>>1, wn = wv&1;
  char* Ab0 = smem;            char* Ab1 = smem + 10240;
  char* Bb0 = smem + 20480;    char* Bb1 = smem + 28672;
  f32x4 z = {0.f,0.f,0.f,0.f};
  #pragma unroll
  for(int m=0;m<4;m++)
    #pragma unroll
    for(int g=0;g<4;g++) acc[m][g]=z;
  SReg sr;
  stage_load(A, ldA, Bp, tid, sr);
  stage_write(Ab0, Bb0, tid, sr);
  const int aoff = (wm*64 + (lane&15))*80 + (lane>>4)*16;
  const int boff = wn*1024 + lane*16;
  for(int ks=0; ks<nks; ks++){
    char* Ac = (ks&1)? Ab1: Ab0;
    char* Bc = (ks&1)? Bb1: Bb0;
    char* An = (ks&1)? Ab0: Ab1;
    char* Bn = (ks&1)? Bb0: Bb1;
    bool more = (ks+1)<nks;
    if(more) stage_load(A + (ks+1)*32, ldA, Bp + (size_t)(ks+1)*4096, tid, sr);
    __syncthreads();
    bf16x8 af[4], bfr[4];
    #pragma unroll
    for(int mt=0;mt<4;mt++) af[mt] = *(const bf16x8*)(Ac + aoff + mt*16*80);
    #pragma unroll
    for(int g=0;g<4;g++)    bfr[g] = *(const bf16x8*)(Bc + boff + g*2048);
    #pragma unroll
    for(int mt=0;mt<4;mt++)
      #pragma unroll
      for(int g=0;g<4;g++)
        acc[mt][g] = __builtin_amdgcn_mfma_f32_16x16x32_bf16(af[mt], bfr[g], acc[mt][g], 0,0,0);
    if(more) stage_write(An, Bn, tid, sr);
  }
}

// ---------------- LSTM epilogue (gate combine fused) ----------------
__device__ __forceinline__ void lstm_epi(f32x4 acc[4][4], int mbase, int jb,
     const float* __restrict__ bias, float* __restrict__ cst,
     bf16* __restrict__ d0, int ld0, bf16* __restrict__ d1, size_t ld1){
  int lane = threadIdx.x&63, wv = threadIdx.x>>6, wm = wv>>1, wn = wv&1;
  int j = jb*32 + wn*16 + (lane&15);
  float bi = bias[j], bff = bias[384+j], bg = bias[768+j], bo = bias[1152+j];
  #pragma unroll
  for(int mt=0;mt<4;mt++){
    #pragma unroll
    for(int r=0;r<4;r++){
      int brow = mbase + wm*64 + mt*16 + (lane>>4)*4 + r;
      float zi = acc[mt][0][r]+bi, zf = acc[mt][1][r]+bff,
            zg = acc[mt][2][r]+bg, zo = acc[mt][3][r]+bo;
      size_t ci = (size_t)brow*HID + j;
      float cold = cst[ci];
      float cn = sigf(zf)*cold + sigf(zi)*tanh_f(zg);
      cst[ci] = cn;
      bf16 hb = (bf16)(sigf(zo)*tanh_f(cn));
      d0[(size_t)brow*ld0 + j] = hb;
      if(d1) d1[(size_t)brow*ld1 + j] = hb;
    }
  }
}

// ---------------- encoder pipelined window ----------------
// window s: blocks 0..95  -> layer0 @ t=s   (skip if s==336)
//           blocks 96..191-> layer1 @ t=s-1 (skip if s==0)
__global__ __launch_bounds__(256)
void enc_window_k(int s, const float* __restrict__ x){
  __shared__ char smem[SMEM_BYTES];
  int bid = blockIdx.x;
  int rs = s&1, wsl = rs^1;
  f32x4 acc[4][4];
  if(bid < 96){
    if(s >= LSEQ) return;
    int mb = bid/12, jb = bid%12;
    const bf16* A = g_A0 + (size_t)rs*NB*416 + (size_t)mb*128*416;
    gemm_core(A, 416, g_Bp0 + (size_t)jb*13*4096, 13, smem, acc);
    lstm_epi(acc, mb*128, jb, g_bias0, g_c0,
             g_A0 + (size_t)wsl*NB*416, 416,
             g_A1 + (size_t)wsl*NB*768, 768);
    if(jb==0 && (s+1)<LSEQ){
      int r = threadIdx.x;
      if(r<128){
        int b = mb*128 + r;
        const float* xs = x + ((size_t)b*LSEQ + (s+1))*8;
        bf16* xd = g_A0 + (size_t)wsl*NB*416 + (size_t)b*416 + 384;
        #pragma unroll
        for(int k=0;k<8;k++) xd[k] = (bf16)xs[k];
      }
    }
  } else {
    if(s < 1) return;
    int b2 = bid-96, mb = b2/12, jb = b2%12;
    const bf16* A = g_A1 + (size_t)rs*NB*768 + (size_t)mb*128*768;
    gemm_core(A, 768, g_Bp1 + (size_t)jb*24*4096, 24, smem, acc);
    lstm_epi(acc, mb*128, jb, g_bias1, g_c1,
             g_A1 + (size_t)wsl*NB*768 + 384, 768,
             g_enc + (size_t)(s-1)*HID, (size_t)LSEQ*HID);
  }
}

// ---------------- decoder LSTM ----------------
__global__ __launch_bounds__(256)
void dec_lstm_k(int t){
  __shared__ char smem[SMEM_BYTES];
  int bid = blockIdx.x, mb = bid/12, jb = bid%12;
  int rs = t&1, wsl = rs^1;
  f32x4 acc[4][4];
  gemm_core(g_Adec + (size_t)rs*NB*768 + (size_t)mb*128*768, 768,
            g_Bpd + (size_t)jb*24*4096, 24, smem, acc);
  lstm_epi(acc, mb*128, jb, g_biasd, g_cdec,
           g_Adec + (size_t)wsl*NB*768 + 384, 768, (bf16*)nullptr, 0);
}

// ---------------- plain GEMM: mode 1 = u-proj (h@Wa -> g_u f32), mode 0 = dec_in relu ----------------
__global__ __launch_bounds__(256)
void plain_gemm_k(int t, int mode){
  __shared__ char smem[SMEM_BYTES];
  int bid = blockIdx.x, mb = bid/3, nb = bid%3;
  int rs = t&1;
  const bf16* A; int ldA, nks; const bf16* Bp;
  if(mode==1){ A = g_Adec + (size_t)rs*NB*768 + 384; ldA=768; Bp = g_Bpu; nks=12; }
  else       { A = g_Adin;                           ldA=416; Bp = g_Bpi; nks=13; }
  f32x4 acc[4][4];
  gemm_core(A + (size_t)mb*128*ldA, ldA, Bp + (size_t)nb*nks*4096, nks, smem, acc);
  int lane = threadIdx.x&63, wv = threadIdx.x>>6, wm = wv>>1, wn = wv&1;
  bf16* dbf = g_Adec + (size_t)rs*NB*768;   // mode 0 dest (din part), ld 768
  #pragma unroll
  for(int mt=0;mt<4;mt++){
    #pragma unroll
    for(int ti=0;ti<4;ti++){
      int n = nb*128 + (ti*2+wn)*16 + (lane&15);
      #pragma unroll
      for(int r=0;r<4;r++){
        int brow = mb*128 + wm*64 + mt*16 + (lane>>4)*4 + r;
        float v = acc[mt][ti][r];
        if(mode==0){ v += g_biasdin[n]; v = fmaxf(v,0.f); dbf[(size_t)brow*768 + n] = (bf16)v; }
        else g_u[(size_t)brow*384 + n] = v;
      }
    }
  }
}

// ---------------- attention: fused scores+softmax+ctx (online) ----------------
// grid 512 blocks x 256thr; each block: 2 batch rows x 2 L-halves (wave each)
__global__ __launch_bounds__(256)
void attn_k(){
  __shared__ float sm[4][392];
  int tid = threadIdx.x, lane = tid&63, w = tid>>6;
  int bl = w>>1, hf = w&1;
  int b = blockIdx.x*2 + bl;
  const float* ub = g_u + (size_t)b*HID + lane*6;
  float u0=ub[0],u1=ub[1],u2=ub[2],u3=ub[3],u4=ub[4],u5=ub[5];
  const u32* er = (const u32*)(g_enc + (size_t)b*LSEQ*HID) + (size_t)hf*168*192 + lane*3;
  float m=-1e30f, den=0.f, a0=0,a1=0,a2=0,a3=0,a4=0,a5=0;
  for(int l=0;l<168;l++){
    u32 w0 = er[0], w1 = er[1], w2 = er[2];
    er += 192;
    float e0 = __uint_as_float(w0<<16);
    float e1 = __uint_as_float(w0 & 0xffff0000u);
    float e2 = __uint_as_float(w1<<16);
    float e3 = __uint_as_float(w1 & 0xffff0000u);
    float e4 = __uint_as_float(w2<<16);
    float e5 = __uint_as_float(w2 & 0xffff0000u);
    float p = e0*u0 + e1*u1 + e2*u2 + e3*u3 + e4*u4 + e5*u5;
    #pragma unroll
    for(int o=1;o<64;o<<=1) p += __shfl_xor(p, o, 64);
    float mn = fmaxf(m, p);
    float al = __expf(m - mn), pe = __expf(p - mn);
    den = den*al + pe;
    a0 = a0*al + pe*e0; a1 = a1*al + pe*e1; a2 = a2*al + pe*e2;
    a3 = a3*al + pe*e3; a4 = a4*al + pe*e4; a5 = a5*al + pe*e5;
    m = mn;
  }
  if(lane==0){ sm[w][0]=m; sm[w][1]=den; }
  sm[w][2+lane*6+0]=a0; sm[w][2+lane*6+1]=a1; sm[w][2+lane*6+2]=a2;
  sm[w][2+lane*6+3]=a3; sm[w][2+lane*6+4]=a4; sm[w][2+lane*6+5]=a5;
  __syncthreads();
  if(hf==0){
    float m2 = sm[w+1][0], d2 = sm[w+1][1];
    float M = fmaxf(m, m2);
    float f1 = __expf(m - M), f2 = __expf(m2 - M);
    float inv = 1.f/(den*f1 + d2*f2);
    bf16* cd = g_Adin + (size_t)b*416 + 5 + lane*6;
    cd[0] = (bf16)((a0*f1 + sm[w+1][2+lane*6+0]*f2)*inv);
    cd[1] = (bf16)((a1*f1 + sm[w+1][2+lane*6+1]*f2)*inv);
    cd[2] = (bf16)((a2*f1 + sm[w+1][2+lane*6+2]*f2)*inv);
    cd[3] = (bf16)((a3*f1 + sm[w+1][2+lane*6+3]*f2)*inv);
    cd[4] = (bf16)((a4*f1 + sm[w+1][2+lane*6+4]*f2)*inv);
    cd[5] = (bf16)((a5*f1 + sm[w+1][2+lane*6+5]*f2)*inv);
  }
}

// ---------------- output head + next-step A_din fill ----------------
__global__ void post_k(int t, const float* __restrict__ outW,
                       const float* __restrict__ outb, float* __restrict__ out,
                       const float* __restrict__ ff){
  int b = blockIdx.x*256 + threadIdx.x;
  if(b>=NB) return;
  int wsl = (t&1)^1;
  const s16x8* hp = (const s16x8*)(g_Adec + (size_t)wsl*NB*768 + (size_t)b*768 + 384);
  float acc = 0.f;
  #pragma unroll 4
  for(int i=0;i<48;i++){
    s16x8 v = hp[i];
    #pragma unroll
    for(int e=0;e<8;e++){
      float hv = __uint_as_float(((u32)(uint16_t)v[e])<<16);
      acc += hv*outW[i*8+e];
    }
  }
  float y = acc + outb[0];
  out[(size_t)b*HOR + t] = y;
  g_Adin[(size_t)b*416] = (bf16)y;
  if(t+1<HOR){
    #pragma unroll
    for(int k=0;k<4;k++) g_Adin[(size_t)b*416 + 1 + k] = (bf16)ff[(size_t)b*HOR*4 + (t+1)*4 + k];
  }
}

// ---------------- decoder init: h_dec = enc h_last; feats(t=0); y_prev=0 ----------------
__global__ void dec_prep_k(const float* __restrict__ ff){
  int i = blockIdx.x*256 + threadIdx.x;
  if(i < NB*HID){
    int b = i/HID, j = i%HID;
    g_Adec[(size_t)b*768 + 384 + j] = g_A1[(size_t)1*NB*768 + (size_t)b*768 + 384 + j];
  }
  if(i < NB*4){
    int b = i>>2, k = i&3;
    g_Adin[(size_t)b*416 + 1 + k] = (bf16)ff[(size_t)b*HOR*4 + k];
  }
  if(i < NB) g_Adin[(size_t)i*416] = (bf16)0.f;
}

extern "C" void kernel_launch(void* const* d_in, const int* in_sizes, int n_in,
                              void* d_out, int out_size, void* d_ws, size_t ws_size,
                              hipStream_t stream){
  const float* x    = (const float*)d_in[0];
  const float* ff   = (const float*)d_in[1];
  const float* Wih0 = (const float*)d_in[2];
  const float* Whh0 = (const float*)d_in[3];
  const float* bih0 = (const float*)d_in[4];
  const float* bhh0 = (const float*)d_in[5];
  const float* Wih1 = (const float*)d_in[6];
  const float* Whh1 = (const float*)d_in[7];
  const float* bih1 = (const float*)d_in[8];
  const float* bhh1 = (const float*)d_in[9];
  const float* Wa   = (const float*)d_in[10];
  const float* dinW = (const float*)d_in[11];
  const float* dinb = (const float*)d_in[12];
  const float* dWih = (const float*)d_in[13];
  const float* dWhh = (const float*)d_in[14];
  const float* dbih = (const float*)d_in[15];
  const float* dbhh = (const float*)d_in[16];
  const float* outW = (const float*)d_in[17];
  const float* outb = (const float*)d_in[18];
  float* out = (float*)d_out;

  zero_state_k<<<1024,256,0,stream>>>();
  pack_gates_k<<<(12*13*512)/256,256,0,stream>>>(0, Whh0, Wih0, 13);
  pack_gates_k<<<(12*24*512)/256,256,0,stream>>>(1, Wih1, Whh1, 24);
  pack_gates_k<<<(12*24*512)/256,256,0,stream>>>(2, dWih, dWhh, 24);
  pack_plain_k<<<(3*13*512)/256,256,0,stream>>>(0, dinW, 13, 3);
  pack_plain_k<<<(3*12*512)/256,256,0,stream>>>(1, Wa, 12, 3);
  prep_misc_k<<<32,256,0,stream>>>(bih0,bhh0,bih1,bhh1,dbih,dbhh,dinb,x);
  for(int s=0;s<=LSEQ;s++)
    enc_window_k<<<192,256,0,stream>>>(s, x);
  dec_prep_k<<<1536,256,0,stream>>>(ff);
  for(int t=0;t<HOR;t++){
    plain_gemm_k<<<24,256,0,stream>>>(t, 1);
    attn_k<<<512,256,0,stream>>>();
    plain_gemm_k<<<24,256,0,stream>>>(t, 0);
    dec_lstm_k<<<96,256,0,stream>>>(t);
    post_k<<<4,256,0,stream>>>(t, outW, outb, out, ff);
  }
  (void)in_sizes; (void)n_in; (void)out_size; (void)d_ws; (void)ws_size;
}